// Round 22
// baseline (181.482 us; speedup 1.0000x reference)
//
#include <hip/hip_runtime.h>
#include <math.h>

#define BN_EPS 1e-5f
#define FIXC 1.0e-4f   // flag threshold: ~7.7 sigma of single-product f16 GEMM error

typedef _Float16 f16;
typedef _Float16 f16x4 __attribute__((ext_vector_type(4)));
typedef _Float16 f16x8 __attribute__((ext_vector_type(8)));
typedef float f32x4 __attribute__((ext_vector_type(4)));
typedef int i32x4 __attribute__((ext_vector_type(4)));

static constexpr int BB = 16;    // batch
static constexpr int C  = 512;   // channels
static constexpr int NP = 1024;  // pixels H*W
static constexpr int NH = 8;     // heads
static constexpr int HD = 64;    // head dim
static constexpr int M3 = 1536;  // 3*C

// Fragment-major layout for f16 GEMM operands:
//   buf[tile128][kt (k/32)][blk ((row%128)/16)][lane][8]
//   lane = (row&15) | (((k&31)>>3)<<4), elem = k&7
// One [tile][kt] block = 8*64*8 = 4096 f16 = 8KB.

// ---- workspace layout (bytes) ----
static constexpr size_t OFF_WHI  = 0;          // f16 frag [12][16][8][64][8]
static constexpr size_t OFF_WPH  = 3145728;    // f16 frag [4][16][8][64][8]
static constexpr size_t OFF_SB   = 3670016;    // f32 s[1536], b[1536]
static constexpr size_t OFF_WN   = 3682304;    // f32 wnorm[1024] (q/k rows)
static constexpr size_t OFF_XN   = 3686400;    // f32 xnorm2[16][1024]
static constexpr size_t OFF_FLAG = 3751936;    // u32 flag bitmap [16][1024][32]
static constexpr size_t OFF_XTH  = 5849088;    // f16 frag [16][8][16][8][64][8]
static constexpr size_t OFF_AOT  = OFF_XTH;    // f16 frag (alias; XtH dead after fix)
static constexpr size_t OFF_Q    = 39403520;   // i8  [16][512][1024]
static constexpr size_t OFF_K    = 47792128;   // i8  [16][512][1024]
static constexpr size_t OFF_VT   = 56180736;   // f16 [16][1024][512]  (v, n-major)

__device__ __forceinline__ void gld16(const void* g, void* l) {
  __builtin_amdgcn_global_load_lds(
      (const __attribute__((address_space(1))) void*)g,
      (__attribute__((address_space(3))) void*)l, 16, 0, 0);
}

__device__ __forceinline__ size_t frag_off(int tile, int kt, int row7, int k5) {
  // row7 = row%128, k5 = k%32 (k5 multiple of 8)
  return (((size_t)tile * 16 + kt) * 8 + (row7 >> 4)) * 512
       + (size_t)((row7 & 15) | ((k5 >> 3) << 4)) * 8;
}

// ---------------------------------------------------------------------------
// conv W: wqkv fp32 -> Whi (frag); wproj -> Wph (frag); BN s/b; q/k row norms.
// ---------------------------------------------------------------------------
__global__ __launch_bounds__(256) void k_convW(
    const float* __restrict__ wqkv, const float* __restrict__ wproj,
    const float* __restrict__ g, const float* __restrict__ be,
    const float* __restrict__ mu, const float* __restrict__ va,
    f16* __restrict__ Whi, f16* __restrict__ Wph,
    float* __restrict__ sA, float* __restrict__ bA, float* __restrict__ wnorm)
{
  const int i = blockIdx.x * 256 + threadIdx.x;
  {
    const int m = i >> 6, l = i & 63;
    const float4 v0 = *(const float4*)&wqkv[(size_t)m * C + l * 8];
    const float4 v1 = *(const float4*)&wqkv[(size_t)m * C + l * 8 + 4];
    const float vv[8] = {v0.x, v0.y, v0.z, v0.w, v1.x, v1.y, v1.z, v1.w};
    f16x8 hv;
    float s2 = 0.f;
#pragma unroll
    for (int q = 0; q < 8; ++q) {
      hv[q] = (f16)vv[q];
      s2 = fmaf(vv[q], vv[q], s2);
    }
    *(f16x8*)&Whi[frag_off(m >> 7, l >> 2, m & 127, (l & 3) * 8)] = hv;
    if (m < 1024) {
      s2 += __shfl_xor(s2, 1);  s2 += __shfl_xor(s2, 2);
      s2 += __shfl_xor(s2, 4);  s2 += __shfl_xor(s2, 8);
      s2 += __shfl_xor(s2, 16); s2 += __shfl_xor(s2, 32);
      if (l == 0) wnorm[m] = sqrtf(s2);
    }
  }
  if (i < 32768) {
    const int m = i >> 6, l = i & 63;
    const float4 v0 = *(const float4*)&wproj[(size_t)m * C + l * 8];
    const float4 v1 = *(const float4*)&wproj[(size_t)m * C + l * 8 + 4];
    const float vv[8] = {v0.x, v0.y, v0.z, v0.w, v1.x, v1.y, v1.z, v1.w};
    f16x8 hv;
#pragma unroll
    for (int q = 0; q < 8; ++q) hv[q] = (f16)vv[q];
    *(f16x8*)&Wph[frag_off(m >> 7, l >> 2, m & 127, (l & 3) * 8)] = hv;
  }
  if (i < M3) {
    const float s = g[i] / sqrtf(va[i] + BN_EPS);
    sA[i] = s;
    bA[i] = be[i] - mu[i] * s;
  }
}

// ---------------------------------------------------------------------------
// conv X: fp32 [b][k][n] -> XtH (frag); column norms^2.
// ---------------------------------------------------------------------------
__global__ __launch_bounds__(256) void k_convX(
    const float* __restrict__ x, f16* __restrict__ XtH,
    float* __restrict__ xnorm2)
{
  const int k0 = blockIdx.x * 64, n0 = blockIdx.y * 64, b = blockIdx.z;
  __shared__ float ls[64][65];
  const int t = threadIdx.x;
  const float* xp = x + ((size_t)b * C + k0) * NP + n0;
  const int c4 = (t & 15) * 4, r0 = t >> 4;
#pragma unroll
  for (int q = 0; q < 4; ++q) {
    const float4 v = *(const float4*)(xp + (size_t)(r0 + q * 16) * NP + c4);
    ls[r0 + q * 16][c4 + 0] = v.x; ls[r0 + q * 16][c4 + 1] = v.y;
    ls[r0 + q * 16][c4 + 2] = v.z; ls[r0 + q * 16][c4 + 3] = v.w;
  }
  __syncthreads();
  if (t < 64) {
    float s2 = 0.f;
#pragma unroll
    for (int q = 0; q < 64; ++q) { const float v = ls[q][t]; s2 = fmaf(v, v, s2); }
    atomicAdd(&xnorm2[(b << 10) + n0 + t], s2);
  }
  const int n = t >> 2, kk = (t & 3) * 16;
  const int n_abs = n0 + n;
  f16x8 hv0 = {}, hv1 = {};
#pragma unroll
  for (int q = 0; q < 8; ++q) hv0[q] = (f16)ls[kk + q][n];
#pragma unroll
  for (int q = 0; q < 8; ++q) hv1[q] = (f16)ls[kk + 8 + q][n];
  const int kb0 = k0 + kk, kb1 = k0 + kk + 8;
  *(f16x8*)&XtH[frag_off(b * 8 + (n_abs >> 7), kb0 >> 5, n_abs & 127, kb0 & 31)] = hv0;
  *(f16x8*)&XtH[frag_off(b * 8 + (n_abs >> 7), kb1 >> 5, n_abs & 127, kb1 & 31)] = hv1;
}

// ---------------------------------------------------------------------------
// qkv GEMM, HYBRID paths + SINGLE-BARRIER 3-buffer rotation (R21 best).
// ---------------------------------------------------------------------------
__global__ __launch_bounds__(256, 3) void k_qkv_mfma(
    const f16* __restrict__ Whi, const f16* __restrict__ XtH,
    const float* __restrict__ sA, const float* __restrict__ bA,
    const float* __restrict__ wnorm, const float* __restrict__ xnorm2,
    signed char* __restrict__ qw, signed char* __restrict__ kw,
    f16* __restrict__ vt, unsigned* __restrict__ flagbits)
{
  __shared__ __align__(16) f16 SMEM[24576];  // B buf0/1/2, 8192 f16 each

  const int t = threadIdx.x, lane = t & 63, wid = t >> 6;
  const int n0 = blockIdx.x * 128, m0 = blockIdx.y * 128, b = blockIdx.z;

  const f16* Af = Whi + (size_t)(m0 >> 7) * 65536;            // [16 kt][4096]
  const f16* Bf = XtH + ((size_t)b * 8 + (n0 >> 7)) * 65536;

  f32x4 acc[4][4];
#pragma unroll
  for (int i = 0; i < 4; ++i)
#pragma unroll
    for (int j = 0; j < 4; ++j) acc[i][j] = (f32x4){0.f, 0.f, 0.f, 0.f};

  const int wm = wid >> 1, wn = wid & 1;
  const int lr = lane & 15, ls = lane >> 4;

#define ALOAD(TI, AR) do {                                              \
    _Pragma("unroll")                                                   \
    for (int u_ = 0; u_ < 8; ++u_)                                      \
      (AR)[u_] = *(const f16x8*)&Af[(size_t)(TI) * 8192 +               \
          ((u_ >> 2) * 8 + wm * 4 + (u_ & 3)) * 512 + lane * 8];        \
  } while (0)

#define BSTAGE(TI, K) do {                                              \
    const f16* Bk_ = Bf + (size_t)(TI) * 8192;                          \
    _Pragma("unroll")                                                   \
    for (int r_ = 0; r_ < 4; ++r_)                                      \
      gld16(Bk_ + r_ * 2048 + t * 8, &SMEM[(K) * 8192 + r_ * 2048 + wid * 512]); \
  } while (0)

#define QCOMP(AR, K) do {                                               \
    _Pragma("unroll")                                                   \
    for (int ksub_ = 0; ksub_ < 2; ++ksub_) {                           \
      f16x8 bh_[4];                                                     \
      _Pragma("unroll")                                                 \
      for (int j_ = 0; j_ < 4; ++j_)                                    \
        bh_[j_] = *(const f16x8*)&SMEM[(K) * 8192 + ksub_ * 4096 +      \
            (wn * 4 + j_) * 512 + lane * 8];                            \
      _Pragma("unroll")                                                 \
      for (int i_ = 0; i_ < 4; ++i_)                                    \
        _Pragma("unroll")                                               \
        for (int j_ = 0; j_ < 4; ++j_)                                  \
          acc[i_][j_] = __builtin_amdgcn_mfma_f32_16x16x32_f16(         \
              (AR)[ksub_ * 4 + i_], bh_[j_], acc[i_][j_], 0, 0, 0);     \
    }                                                                   \
  } while (0)

  {
    f16x8 a0[8], a1[8];
    ALOAD(0, a0);          // A(0): 8 loads
    BSTAGE(0, 0);          // B(0): 4
    BSTAGE(1, 1);          // B(1): 4
#pragma unroll
    for (int ti = 0; ti < 8; ++ti) {
      if (ti == 0)      asm volatile("s_waitcnt vmcnt(4)"  ::: "memory");
      else if (ti < 7)  asm volatile("s_waitcnt vmcnt(12)" ::: "memory");
      else              asm volatile("s_waitcnt vmcnt(0)"  ::: "memory");
      __builtin_amdgcn_sched_barrier(0);
      __builtin_amdgcn_s_barrier();        // B(ti) landed; buf[(ti+2)%3] free
      if (ti + 1 < 8) { if ((ti + 1) & 1) ALOAD(ti + 1, a1); else ALOAD(ti + 1, a0); }
      if (ti + 2 < 8) BSTAGE(ti + 2, (ti + 2) % 3);
      if (ti & 1) QCOMP(a1, ti % 3); else QCOMP(a0, ti % 3);
    }
  }

#undef ALOAD
#undef BSTAGE
#undef QCOMP

  const int kidx = m0 >> 9;   // 0=q 1=k 2=v (uniform per block)
  if (kidx != 2) {
    signed char* dst0 = (kidx == 0) ? qw : kw;
    float xnrm[4];
#pragma unroll
    for (int j = 0; j < 4; ++j)
      xnrm[j] = sqrtf(xnorm2[(b << 10) + n0 + wn * 64 + j * 16 + lr]);
#pragma unroll
    for (int i = 0; i < 4; ++i) {
      float sv[4], bv[4], dl[4];
#pragma unroll
      for (int r = 0; r < 4; ++r) {
        const int o = m0 + wm * 64 + i * 16 + ls * 4 + r;
        sv[r] = sA[o]; bv[r] = bA[o];
        dl[r] = FIXC * wnorm[o] * sv[r];
      }
      const int oc0 = (m0 & 511) + wm * 64 + i * 16 + ls * 4;
      const int og0 = m0 + wm * 64 + i * 16 + ls * 4;
#pragma unroll
      for (int j = 0; j < 4; ++j) {
        const int n = n0 + wn * 64 + j * 16 + lr;
#pragma unroll
        for (int r = 0; r < 4; ++r) {
          const float z = fmaf(acc[i][j][r], sv[r], bv[r]);
          dst0[((size_t)b * C + oc0 + r) * NP + n] =
              (signed char)((z > 0.f) - (z < 0.f));
          if (fabsf(z) <= dl[r] * xnrm[j]) {
            const int of = og0 + r;
            atomicOr(&flagbits[(((size_t)b * NP + n) << 5) + (of >> 5)],
                     1u << (of & 31));
          }
        }
      }
    }
  } else {
    // v: BN + f16, transpose 64-row halves through LDS, write vt[b][n][c]
    const int c0 = m0 & 511;
    for (int hf = 0; hf < 2; ++hf) {
      __syncthreads();
      if (wn == hf) {
#pragma unroll
        for (int i = 0; i < 4; ++i) {
          float sv[4], bv[4];
#pragma unroll
          for (int r = 0; r < 4; ++r) {
            const int o = m0 + wm * 64 + i * 16 + ls * 4 + r;
            sv[r] = sA[o]; bv[r] = bA[o];
          }
#pragma unroll
          for (int j = 0; j < 4; ++j) {
            f16x4 pk;
#pragma unroll
            for (int r = 0; r < 4; ++r)
              pk[r] = (f16)fmaf(acc[i][j][r], sv[r], bv[r]);
            *(f16x4*)&SMEM[(size_t)(j * 16 + lr) * 136 + wm * 64 + i * 16 + ls * 4] = pk;
          }
        }
      }
      __syncthreads();
      const int nl = t >> 2, cc = (t & 3) * 32;
      const f16* src = &SMEM[(size_t)nl * 136 + cc];
      f16x8 r0 = *(const f16x8*)(src + 0);
      f16x8 r1 = *(const f16x8*)(src + 8);
      f16x8 r2 = *(const f16x8*)(src + 16);
      f16x8 r3 = *(const f16x8*)(src + 24);
      f16* dstv = vt + ((size_t)b * NP + n0 + hf * 64 + nl) * C + c0 + cc;
      *(f16x8*)(dstv + 0)  = r0;
      *(f16x8*)(dstv + 8)  = r1;
      *(f16x8*)(dstv + 16) = r2;
      *(f16x8*)(dstv + 24) = r3;
    }
  }
}

// ---------------------------------------------------------------------------
// fix: recompute flagged q/k elements EXACTLY in fp32 from the original
// wqkv (contiguous rows) and x (strided columns, L3-resident).
// ---------------------------------------------------------------------------
__global__ __launch_bounds__(256) void k_fix(
    const unsigned* __restrict__ flagbits,
    const float* __restrict__ wqkv, const float* __restrict__ x,
    const float* __restrict__ sA, const float* __restrict__ bA,
    signed char* __restrict__ qw, signed char* __restrict__ kw)
{
  const int wv = blockIdx.x * 4 + (threadIdx.x >> 6);   // (b,n) column id
  const int lane = threadIdx.x & 63;                    // k = lane*8
  const int b = wv >> 10, n = wv & 1023;

  const unsigned* bm = flagbits + ((size_t)wv << 5);
  const unsigned myw = (lane < 32) ? bm[lane] : 0u;
  if (__ballot(myw != 0) == 0ULL) return;

  const int kb = lane * 8;
  float xv[8];
#pragma unroll
  for (int q = 0; q < 8; ++q)
    xv[q] = x[((size_t)b * C + kb + q) * NP + n];

  for (int w = 0; w < 32; ++w) {
    unsigned bits = __shfl(myw, w);
    while (bits) {
      const int o = w * 32 + __builtin_ctz(bits);
      bits &= bits - 1;
      const float4 w0 = *(const float4*)&wqkv[(size_t)o * C + kb];
      const float4 w1 = *(const float4*)&wqkv[(size_t)o * C + kb + 4];
      float s = 0.f;
      s = fmaf(w0.x, xv[0], s); s = fmaf(w0.y, xv[1], s);
      s = fmaf(w0.z, xv[2], s); s = fmaf(w0.w, xv[3], s);
      s = fmaf(w1.x, xv[4], s); s = fmaf(w1.y, xv[5], s);
      s = fmaf(w1.z, xv[6], s); s = fmaf(w1.w, xv[7], s);
      s += __shfl_xor(s, 1);  s += __shfl_xor(s, 2);  s += __shfl_xor(s, 4);
      s += __shfl_xor(s, 8);  s += __shfl_xor(s, 16); s += __shfl_xor(s, 32);
      if (lane == 0) {
        const float y = fmaf(s, sA[o], bA[o]);
        const signed char sg = (signed char)((y > 0.f) - (y < 0.f));
        if (o < 512) qw[((size_t)b * C + o) * NP + n] = sg;
        else         kw[((size_t)b * C + (o - 512)) * NP + n] = sg;
      }
    }
  }
}

// ---------------------------------------------------------------------------
// Fused attention: per (b,h, n-half): S = q.k^T via i8 MFMA (exact),
// wave-parallel softmax, P -> f16 hi/lo in LDS, PV via f16 MFMA.
// Output written in frag layout (proj's B operand).
// ---------------------------------------------------------------------------
__global__ __launch_bounds__(256) void k_attn_fused(
    const signed char* __restrict__ qw, const signed char* __restrict__ kw,
    const f16* __restrict__ vt, f16* __restrict__ aot)
{
  const int half = blockIdx.x;
  const int bh = blockIdx.y;
  const int b = bh >> 3, h = bh & 7;
  const int t = threadIdx.x, lane = t & 63, wid = t >> 6;
  const int dw = wid * 16;
  const int lr = lane & 15, lg = lane >> 4;

  __shared__ f16 ph[64][72];
  __shared__ f16 pl[64][72];
  __shared__ f16 sb[64][72];

  const signed char* qp = qw + ((size_t)b * C + h * HD + dw + lr) * NP;
  const signed char* kp = kw + ((size_t)b * C + h * HD + lr) * NP;

  i32x4 accS[4];
#pragma unroll
  for (int j = 0; j < 4; ++j) accS[j] = (i32x4){0, 0, 0, 0};

#pragma unroll 4
  for (int ks = 0; ks < 16; ++ks) {
    const i32x4 af = *(const i32x4*)(qp + ks * 64 + lg * 16);
#pragma unroll
    for (int j = 0; j < 4; ++j) {
      const i32x4 bf = *(const i32x4*)(kp + (size_t)(j * 16) * NP + ks * 64 + lg * 16);
      accS[j] = __builtin_amdgcn_mfma_i32_16x16x64_i8(af, bf, accS[j], 0, 0, 0);
    }
  }

#pragma unroll
  for (int r = 0; r < 4; ++r) {
    float mx = (float)accS[0][r];
#pragma unroll
    for (int j = 1; j < 4; ++j) mx = fmaxf(mx, (float)accS[j][r]);
    mx = fmaxf(mx, __shfl_xor(mx, 1));
    mx = fmaxf(mx, __shfl_xor(mx, 2));
    mx = fmaxf(mx, __shfl_xor(mx, 4));
    mx = fmaxf(mx, __shfl_xor(mx, 8));
    float pvv[4];
    float sm = 0.f;
#pragma unroll
    for (int j = 0; j < 4; ++j) {
      pvv[j] = expf(((float)accS[j][r] - mx) * 0.125f);
      sm += pvv[j];
    }
    sm += __shfl_xor(sm, 1);
    sm += __shfl_xor(sm, 2);
    sm += __shfl_xor(sm, 4);
    sm += __shfl_xor(sm, 8);
    const float inv = 1.f / sm;
    const int drow = dw + lg * 4 + r;
#pragma unroll
    for (int j = 0; j < 4; ++j) {
      const float p = pvv[j] * inv;
      const f16 hi = (f16)p;
      ph[drow][j * 16 + lr] = hi;
      pl[drow][j * 16 + lr] = (f16)(p - (float)hi);
    }
  }
  __syncthreads();

  const f16x8 pa0h = *(const f16x8*)&ph[dw + lr][lg * 8];
  const f16x8 pa0l = *(const f16x8*)&pl[dw + lr][lg * 8];
  const f16x8 pa1h = *(const f16x8*)&ph[dw + lr][32 + lg * 8];
  const f16x8 pa1l = *(const f16x8*)&pl[dw + lr][32 + lg * 8];

  const f16* vbase = vt + (size_t)b * NP * C + h * HD;
  const int nbase = half * 512;

  for (int nc = 0; nc < 8; ++nc) {
    const int nn0 = nbase + nc * 64;
    __syncthreads();
#pragma unroll
    for (int nt = 0; nt < 4; ++nt) {
      const f16* vp = vbase + (size_t)(nn0 + nt * 16 + lr) * C + lg * 8;
      const f16x8 bv0 = *(const f16x8*)(vp);
      const f16x8 bv1 = *(const f16x8*)(vp + 32);
      f32x4 acc = (f32x4){0.f, 0.f, 0.f, 0.f};
      acc = __builtin_amdgcn_mfma_f32_16x16x32_f16(pa0h, bv0, acc, 0, 0, 0);
      acc = __builtin_amdgcn_mfma_f32_16x16x32_f16(pa0l, bv0, acc, 0, 0, 0);
      acc = __builtin_amdgcn_mfma_f32_16x16x32_f16(pa1h, bv1, acc, 0, 0, 0);
      acc = __builtin_amdgcn_mfma_f32_16x16x32_f16(pa1l, bv1, acc, 0, 0, 0);
      f16x4 pk;
#pragma unroll
      for (int r = 0; r < 4; ++r) pk[r] = (f16)acc[r];
      *(f16x4*)&sb[nt * 16 + lr][dw + lg * 4] = pk;
    }
    __syncthreads();
    const int nl = t >> 2, cc = (t & 3) * 16;
    const f16x8 o0 = *(const f16x8*)&sb[nl][cc];
    const f16x8 o1 = *(const f16x8*)&sb[nl][cc + 8];
    const int n_abs = nn0 + nl;
    const int c1 = h * HD + cc, c2 = h * HD + cc + 8;
    *(f16x8*)&aot[frag_off(b * 8 + (n_abs >> 7), c1 >> 5, n_abs & 127, c1 & 31)] = o0;
    *(f16x8*)&aot[frag_off(b * 8 + (n_abs >> 7), c2 >> 5, n_abs & 127, c2 & 31)] = o1;
  }
}

// ---------------------------------------------------------------------------
// proj GEMM, HYBRID paths + single-barrier 3-buffer rotation + residual.
// ---------------------------------------------------------------------------
__global__ __launch_bounds__(256, 3) void k_proj_mfma(
    const f16* __restrict__ Wph, const f16* __restrict__ aot,
    const float* __restrict__ X, float* __restrict__ out)
{
  __shared__ __align__(16) f16 SMEM[24576];  // B buf0/1/2, 8192 f16 each

  const int t = threadIdx.x, lane = t & 63, wid = t >> 6;
  const int n0 = blockIdx.x * 128, m0 = blockIdx.y * 128, b = blockIdx.z;

  const f16* Af = Wph + (size_t)(m0 >> 7) * 65536;
  const f16* Bf = aot + ((size_t)b * 8 + (n0 >> 7)) * 65536;

  f32x4 acc[4][4];
#pragma unroll
  for (int i = 0; i < 4; ++i)
#pragma unroll
    for (int j = 0; j < 4; ++j) acc[i][j] = (f32x4){0.f, 0.f, 0.f, 0.f};

  const int wm = wid >> 1, wn = wid & 1;
  const int lr = lane & 15, ls = lane >> 4;

#define ALOAD(TI, AR) do {                                              \
    _Pragma("unroll")                                                   \
    for (int u_ = 0; u_ < 8; ++u_)                                      \
      (AR)[u_] = *(const f16x8*)&Af[(size_t)(TI) * 8192 +               \
          ((u_ >> 2) * 8 + wm * 4 + (u_ & 3)) * 512 + lane * 8];        \
  } while (0)

#define BSTAGE(TI, K) do {                                              \
    const f16* Bk_ = Bf + (size_t)(TI) * 8192;                          \
    _Pragma("unroll")                                                   \
    for (int r_ = 0; r_ < 4; ++r_)                                      \
      gld16(Bk_ + r_ * 2048 + t * 8, &SMEM[(K) * 8192 + r_ * 2048 + wid * 512]); \
  } while (0)

#define PCOMP(AR, K) do {                                               \
    _Pragma("unroll")                                                   \
    for (int ksub_ = 0; ksub_ < 2; ++ksub_) {                           \
      f16x8 bh_[4];                                                     \
      _Pragma("unroll")                                                 \
      for (int j_ = 0; j_ < 4; ++j_)                                    \
        bh_[j_] = *(const f16x8*)&SMEM[(K) * 8192 + ksub_ * 4096 +      \
            (wn * 4 + j_) * 512 + lane * 8];                            \
      _Pragma("unroll")                                                 \
      for (int i_ = 0; i_ < 4; ++i_)                                    \
        _Pragma("unroll")                                               \
        for (int j_ = 0; j_ < 4; ++j_)                                  \
          acc[i_][j_] = __builtin_amdgcn_mfma_f32_16x16x32_f16(         \
              (AR)[ksub_ * 4 + i_], bh_[j_], acc[i_][j_], 0, 0, 0);     \
    }                                                                   \
  } while (0)

  {
    f16x8 a0[8], a1[8];
    ALOAD(0, a0);
    BSTAGE(0, 0);
    BSTAGE(1, 1);
#pragma unroll
    for (int ti = 0; ti < 8; ++ti) {
      if (ti == 0)      asm volatile("s_waitcnt vmcnt(4)"  ::: "memory");
      else if (ti < 7)  asm volatile("s_waitcnt vmcnt(12)" ::: "memory");
      else              asm volatile("s_waitcnt vmcnt(0)"  ::: "memory");
      __builtin_amdgcn_sched_barrier(0);
      __builtin_amdgcn_s_barrier();
      if (ti + 1 < 8) { if ((ti + 1) & 1) ALOAD(ti + 1, a1); else ALOAD(ti + 1, a0); }
      if (ti + 2 < 8) BSTAGE(ti + 2, (ti + 2) % 3);
      if (ti & 1) PCOMP(a1, ti % 3); else PCOMP(a0, ti % 3);
    }
  }

#undef ALOAD
#undef BSTAGE
#undef PCOMP

#pragma unroll
  for (int i = 0; i < 4; ++i) {
    const int oc0 = m0 + wm * 64 + i * 16 + ls * 4;
#pragma unroll
    for (int j = 0; j < 4; ++j) {
      const int n = n0 + wn * 64 + j * 16 + lr;
#pragma unroll
      for (int r = 0; r < 4; ++r) {
        const size_t idx = ((size_t)b * C + oc0 + r) * NP + n;
        out[idx] = acc[i][j][r] + X[idx];
      }
    }
  }
}

// ---------------------------------------------------------------------------
extern "C" void kernel_launch(void* const* d_in, const int* in_sizes, int n_in,
                              void* d_out, int out_size, void* d_ws, size_t ws_size,
                              hipStream_t stream)
{
  const float* x      = (const float*)d_in[0];
  const float* w_qkv  = (const float*)d_in[1];
  const float* w_proj = (const float*)d_in[2];
  const float* g      = (const float*)d_in[3];
  const float* be     = (const float*)d_in[4];
  const float* mu     = (const float*)d_in[5];
  const float* va     = (const float*)d_in[6];
  float* out = (float*)d_out;

  char* ws = (char*)d_ws;
  f16*  Whi = (f16*)(ws + OFF_WHI);
  f16*  Wph = (f16*)(ws + OFF_WPH);
  float* sA = (float*)(ws + OFF_SB);
  float* bA = sA + M3;
  float* wn = (float*)(ws + OFF_WN);
  float* xn2 = (float*)(ws + OFF_XN);
  unsigned* flagbits = (unsigned*)(ws + OFF_FLAG);
  f16*  XtH = (f16*)(ws + OFF_XTH);
  f16*  aot = (f16*)(ws + OFF_AOT);
  signed char* qw = (signed char*)(ws + OFF_Q);
  signed char* kw = (signed char*)(ws + OFF_K);
  f16*  vtw = (f16*)(ws + OFF_VT);

  // xnorm2 and flagbits are contiguous: one memset for both
  hipMemsetAsync(xn2, 0, OFF_XTH - OFF_XN, stream);

  k_convW<<<dim3(384), 256, 0, stream>>>(
      w_qkv, w_proj, g, be, mu, va, Whi, Wph, sA, bA, wn);
  k_convX<<<dim3(C / 64, NP / 64, BB), 256, 0, stream>>>(x, XtH, xn2);
  k_qkv_mfma<<<dim3(NP / 128, M3 / 128, BB), 256, 0, stream>>>(
      Whi, XtH, sA, bA, wn, xn2, qw, kw, vtw, flagbits);
  k_fix<<<dim3(BB * NP / 4), 256, 0, stream>>>(
      flagbits, w_qkv, x, sA, bA, qw, kw);
  k_attn_fused<<<dim3(2, BB * NH), 256, 0, stream>>>(qw, kw, vtw, aot);
  k_proj_mfma<<<dim3(NP / 128, C / 128, BB), 256, 0, stream>>>(Wph, aot, x, out);
}

// Round 23
// 125.410 us; speedup vs baseline: 1.4471x; 1.4471x over previous
//
#include <hip/hip_runtime.h>
#include <math.h>

#define BN_EPS 1e-5f
#define FIXC 1.0e-4f   // flag threshold: ~7.7 sigma of single-product f16 GEMM error

typedef _Float16 f16;
typedef _Float16 f16x4 __attribute__((ext_vector_type(4)));
typedef _Float16 f16x8 __attribute__((ext_vector_type(8)));
typedef float f32x4 __attribute__((ext_vector_type(4)));
typedef int i32x4 __attribute__((ext_vector_type(4)));

static constexpr int BB = 16;    // batch
static constexpr int C  = 512;   // channels
static constexpr int NP = 1024;  // pixels H*W
static constexpr int NH = 8;     // heads
static constexpr int HD = 64;    // head dim
static constexpr int M3 = 1536;  // 3*C

// Fragment-major layout for f16 GEMM operands:
//   buf[tile128][kt (k/32)][blk ((row%128)/16)][lane][8]
//   lane = (row&15) | (((k&31)>>3)<<4), elem = k&7
// One [tile][kt] block = 8*64*8 = 4096 f16 = 8KB.

// ---- workspace layout (bytes) ----
static constexpr size_t OFF_WHI  = 0;          // f16 frag [12][16][8][64][8]
static constexpr size_t OFF_WPH  = 3145728;    // f16 frag [4][16][8][64][8]
static constexpr size_t OFF_SB   = 3670016;    // f32 s[1536], b[1536]
static constexpr size_t OFF_WN   = 3682304;    // f32 wnorm[1024] (q/k rows)
static constexpr size_t OFF_XN   = 3686400;    // f32 xnorm2[16][1024]
static constexpr size_t OFF_FLAG = 3751936;    // u32 flag bitmap [16][1024][32]
static constexpr size_t OFF_XTH  = 5849088;    // f16 frag [16][8][16][8][64][8]
static constexpr size_t OFF_XTL  = 22626304;   // f16 linear [16][1024][512]
static constexpr size_t OFF_AOT  = OFF_XTH;    // f16 frag (alias; XtH dead after fix)
static constexpr size_t OFF_Q    = 39403520;   // i8  [16][512][1024]
static constexpr size_t OFF_K    = 47792128;   // i8  [16][512][1024]
static constexpr size_t OFF_VT   = 56180736;   // f16 [16][1024][512]  (v, n-major)

__device__ __forceinline__ void gld16(const void* g, void* l) {
  __builtin_amdgcn_global_load_lds(
      (const __attribute__((address_space(1))) void*)g,
      (__attribute__((address_space(3))) void*)l, 16, 0, 0);
}

__device__ __forceinline__ size_t frag_off(int tile, int kt, int row7, int k5) {
  // row7 = row%128, k5 = k%32 (k5 multiple of 8)
  return (((size_t)tile * 16 + kt) * 8 + (row7 >> 4)) * 512
       + (size_t)((row7 & 15) | ((k5 >> 3) << 4)) * 8;
}

// ---------------------------------------------------------------------------
// conv W: wqkv fp32 -> Whi (frag); wproj -> Wph (frag); BN s/b; q/k row norms.
// (no Wlo: k_fix reads the original fp32 wqkv rows directly)
// ---------------------------------------------------------------------------
__global__ __launch_bounds__(256) void k_convW(
    const float* __restrict__ wqkv, const float* __restrict__ wproj,
    const float* __restrict__ g, const float* __restrict__ be,
    const float* __restrict__ mu, const float* __restrict__ va,
    f16* __restrict__ Whi, f16* __restrict__ Wph,
    float* __restrict__ sA, float* __restrict__ bA, float* __restrict__ wnorm)
{
  const int i = blockIdx.x * 256 + threadIdx.x;
  {
    const int m = i >> 6, l = i & 63;
    const float4 v0 = *(const float4*)&wqkv[(size_t)m * C + l * 8];
    const float4 v1 = *(const float4*)&wqkv[(size_t)m * C + l * 8 + 4];
    const float vv[8] = {v0.x, v0.y, v0.z, v0.w, v1.x, v1.y, v1.z, v1.w};
    f16x8 hv;
    float s2 = 0.f;
#pragma unroll
    for (int q = 0; q < 8; ++q) {
      hv[q] = (f16)vv[q];
      s2 = fmaf(vv[q], vv[q], s2);
    }
    *(f16x8*)&Whi[frag_off(m >> 7, l >> 2, m & 127, (l & 3) * 8)] = hv;
    if (m < 1024) {
      s2 += __shfl_xor(s2, 1);  s2 += __shfl_xor(s2, 2);
      s2 += __shfl_xor(s2, 4);  s2 += __shfl_xor(s2, 8);
      s2 += __shfl_xor(s2, 16); s2 += __shfl_xor(s2, 32);
      if (l == 0) wnorm[m] = sqrtf(s2);
    }
  }
  if (i < 32768) {
    const int m = i >> 6, l = i & 63;
    const float4 v0 = *(const float4*)&wproj[(size_t)m * C + l * 8];
    const float4 v1 = *(const float4*)&wproj[(size_t)m * C + l * 8 + 4];
    const float vv[8] = {v0.x, v0.y, v0.z, v0.w, v1.x, v1.y, v1.z, v1.w};
    f16x8 hv;
#pragma unroll
    for (int q = 0; q < 8; ++q) hv[q] = (f16)vv[q];
    *(f16x8*)&Wph[frag_off(m >> 7, l >> 2, m & 127, (l & 3) * 8)] = hv;
  }
  if (i < M3) {
    const float s = g[i] / sqrtf(va[i] + BN_EPS);
    sA[i] = s;
    bA[i] = be[i] - mu[i] * s;
  }
}

// ---------------------------------------------------------------------------
// conv X: fp32 [b][k][n] -> XtH (frag) + XtL (linear lo-split, for k_fix);
// column norms^2.
// ---------------------------------------------------------------------------
__global__ __launch_bounds__(256) void k_convX(
    const float* __restrict__ x, f16* __restrict__ XtH, f16* __restrict__ XtL,
    float* __restrict__ xnorm2)
{
  const int k0 = blockIdx.x * 64, n0 = blockIdx.y * 64, b = blockIdx.z;
  __shared__ float ls[64][65];
  const int t = threadIdx.x;
  const float* xp = x + ((size_t)b * C + k0) * NP + n0;
  const int c4 = (t & 15) * 4, r0 = t >> 4;
#pragma unroll
  for (int q = 0; q < 4; ++q) {
    const float4 v = *(const float4*)(xp + (size_t)(r0 + q * 16) * NP + c4);
    ls[r0 + q * 16][c4 + 0] = v.x; ls[r0 + q * 16][c4 + 1] = v.y;
    ls[r0 + q * 16][c4 + 2] = v.z; ls[r0 + q * 16][c4 + 3] = v.w;
  }
  __syncthreads();
  if (t < 64) {
    float s2 = 0.f;
#pragma unroll
    for (int q = 0; q < 64; ++q) { const float v = ls[q][t]; s2 = fmaf(v, v, s2); }
    atomicAdd(&xnorm2[(b << 10) + n0 + t], s2);
  }
  const int n = t >> 2, kk = (t & 3) * 16;
  const int n_abs = n0 + n;
  f16x8 hv0 = {}, hv1 = {}, lv0 = {}, lv1 = {};
#pragma unroll
  for (int q = 0; q < 8; ++q) {
    const float v = ls[kk + q][n];
    const f16 h = (f16)v;
    hv0[q] = h; lv0[q] = (f16)(v - (float)h);
  }
#pragma unroll
  for (int q = 0; q < 8; ++q) {
    const float v = ls[kk + 8 + q][n];
    const f16 h = (f16)v;
    hv1[q] = h; lv1[q] = (f16)(v - (float)h);
  }
  const int kb0 = k0 + kk, kb1 = k0 + kk + 8;
  *(f16x8*)&XtH[frag_off(b * 8 + (n_abs >> 7), kb0 >> 5, n_abs & 127, kb0 & 31)] = hv0;
  *(f16x8*)&XtH[frag_off(b * 8 + (n_abs >> 7), kb1 >> 5, n_abs & 127, kb1 & 31)] = hv1;
  *(f16x8*)&XtL[((size_t)b * NP + n_abs) * C + kb0] = lv0;
  *(f16x8*)&XtL[((size_t)b * NP + n_abs) * C + kb1] = lv1;
}

// ---------------------------------------------------------------------------
// qkv GEMM, HYBRID paths + SINGLE-BARRIER 3-buffer rotation (R21 best).
// ---------------------------------------------------------------------------
__global__ __launch_bounds__(256, 3) void k_qkv_mfma(
    const f16* __restrict__ Whi, const f16* __restrict__ XtH,
    const float* __restrict__ sA, const float* __restrict__ bA,
    const float* __restrict__ wnorm, const float* __restrict__ xnorm2,
    signed char* __restrict__ qw, signed char* __restrict__ kw,
    f16* __restrict__ vt, unsigned* __restrict__ flagbits)
{
  __shared__ __align__(16) f16 SMEM[24576];  // B buf0/1/2, 8192 f16 each

  const int t = threadIdx.x, lane = t & 63, wid = t >> 6;
  const int n0 = blockIdx.x * 128, m0 = blockIdx.y * 128, b = blockIdx.z;

  const f16* Af = Whi + (size_t)(m0 >> 7) * 65536;            // [16 kt][4096]
  const f16* Bf = XtH + ((size_t)b * 8 + (n0 >> 7)) * 65536;

  f32x4 acc[4][4];
#pragma unroll
  for (int i = 0; i < 4; ++i)
#pragma unroll
    for (int j = 0; j < 4; ++j) acc[i][j] = (f32x4){0.f, 0.f, 0.f, 0.f};

  const int wm = wid >> 1, wn = wid & 1;
  const int lr = lane & 15, ls = lane >> 4;

#define ALOAD(TI, AR) do {                                              \
    _Pragma("unroll")                                                   \
    for (int u_ = 0; u_ < 8; ++u_)                                      \
      (AR)[u_] = *(const f16x8*)&Af[(size_t)(TI) * 8192 +               \
          ((u_ >> 2) * 8 + wm * 4 + (u_ & 3)) * 512 + lane * 8];        \
  } while (0)

#define BSTAGE(TI, K) do {                                              \
    const f16* Bk_ = Bf + (size_t)(TI) * 8192;                          \
    _Pragma("unroll")                                                   \
    for (int r_ = 0; r_ < 4; ++r_)                                      \
      gld16(Bk_ + r_ * 2048 + t * 8, &SMEM[(K) * 8192 + r_ * 2048 + wid * 512]); \
  } while (0)

#define QCOMP(AR, K) do {                                               \
    _Pragma("unroll")                                                   \
    for (int ksub_ = 0; ksub_ < 2; ++ksub_) {                           \
      f16x8 bh_[4];                                                     \
      _Pragma("unroll")                                                 \
      for (int j_ = 0; j_ < 4; ++j_)                                    \
        bh_[j_] = *(const f16x8*)&SMEM[(K) * 8192 + ksub_ * 4096 +      \
            (wn * 4 + j_) * 512 + lane * 8];                            \
      _Pragma("unroll")                                                 \
      for (int i_ = 0; i_ < 4; ++i_)                                    \
        _Pragma("unroll")                                               \
        for (int j_ = 0; j_ < 4; ++j_)                                  \
          acc[i_][j_] = __builtin_amdgcn_mfma_f32_16x16x32_f16(         \
              (AR)[ksub_ * 4 + i_], bh_[j_], acc[i_][j_], 0, 0, 0);     \
    }                                                                   \
  } while (0)

  {
    f16x8 a0[8], a1[8];
    ALOAD(0, a0);          // A(0): 8 loads
    BSTAGE(0, 0);          // B(0): 4
    BSTAGE(1, 1);          // B(1): 4
#pragma unroll
    for (int ti = 0; ti < 8; ++ti) {
      if (ti == 0)      asm volatile("s_waitcnt vmcnt(4)"  ::: "memory");
      else if (ti < 7)  asm volatile("s_waitcnt vmcnt(12)" ::: "memory");
      else              asm volatile("s_waitcnt vmcnt(0)"  ::: "memory");
      __builtin_amdgcn_sched_barrier(0);
      __builtin_amdgcn_s_barrier();        // B(ti) landed; buf[(ti+2)%3] free
      if (ti + 1 < 8) { if ((ti + 1) & 1) ALOAD(ti + 1, a1); else ALOAD(ti + 1, a0); }
      if (ti + 2 < 8) BSTAGE(ti + 2, (ti + 2) % 3);
      if (ti & 1) QCOMP(a1, ti % 3); else QCOMP(a0, ti % 3);
    }
  }

#undef ALOAD
#undef BSTAGE
#undef QCOMP

  const int kidx = m0 >> 9;   // 0=q 1=k 2=v (uniform per block)
  if (kidx != 2) {
    signed char* dst0 = (kidx == 0) ? qw : kw;
    float xnrm[4];
#pragma unroll
    for (int j = 0; j < 4; ++j)
      xnrm[j] = sqrtf(xnorm2[(b << 10) + n0 + wn * 64 + j * 16 + lr]);
#pragma unroll
    for (int i = 0; i < 4; ++i) {
      float sv[4], bv[4], dl[4];
#pragma unroll
      for (int r = 0; r < 4; ++r) {
        const int o = m0 + wm * 64 + i * 16 + ls * 4 + r;
        sv[r] = sA[o]; bv[r] = bA[o];
        dl[r] = FIXC * wnorm[o] * sv[r];
      }
      const int oc0 = (m0 & 511) + wm * 64 + i * 16 + ls * 4;
      const int og0 = m0 + wm * 64 + i * 16 + ls * 4;
#pragma unroll
      for (int j = 0; j < 4; ++j) {
        const int n = n0 + wn * 64 + j * 16 + lr;
#pragma unroll
        for (int r = 0; r < 4; ++r) {
          const float z = fmaf(acc[i][j][r], sv[r], bv[r]);
          dst0[((size_t)b * C + oc0 + r) * NP + n] =
              (signed char)((z > 0.f) - (z < 0.f));
          if (fabsf(z) <= dl[r] * xnrm[j]) {
            const int of = og0 + r;
            atomicOr(&flagbits[(((size_t)b * NP + n) << 5) + (of >> 5)],
                     1u << (of & 31));
          }
        }
      }
    }
  } else {
    // v: BN + f16, transpose 64-row halves through LDS, write vt[b][n][c]
    const int c0 = m0 & 511;
    for (int hf = 0; hf < 2; ++hf) {
      __syncthreads();
      if (wn == hf) {
#pragma unroll
        for (int i = 0; i < 4; ++i) {
          float sv[4], bv[4];
#pragma unroll
          for (int r = 0; r < 4; ++r) {
            const int o = m0 + wm * 64 + i * 16 + ls * 4 + r;
            sv[r] = sA[o]; bv[r] = bA[o];
          }
#pragma unroll
          for (int j = 0; j < 4; ++j) {
            f16x4 pk;
#pragma unroll
            for (int r = 0; r < 4; ++r)
              pk[r] = (f16)fmaf(acc[i][j][r], sv[r], bv[r]);
            *(f16x4*)&SMEM[(size_t)(j * 16 + lr) * 136 + wm * 64 + i * 16 + ls * 4] = pk;
          }
        }
      }
      __syncthreads();
      const int nl = t >> 2, cc = (t & 3) * 32;
      const f16* src = &SMEM[(size_t)nl * 136 + cc];
      f16x8 r0 = *(const f16x8*)(src + 0);
      f16x8 r1 = *(const f16x8*)(src + 8);
      f16x8 r2 = *(const f16x8*)(src + 16);
      f16x8 r3 = *(const f16x8*)(src + 24);
      f16* dstv = vt + ((size_t)b * NP + n0 + hf * 64 + nl) * C + c0 + cc;
      *(f16x8*)(dstv + 0)  = r0;
      *(f16x8*)(dstv + 8)  = r1;
      *(f16x8*)(dstv + 16) = r2;
      *(f16x8*)(dstv + 24) = r3;
    }
  }
}

// ---------------------------------------------------------------------------
// fix: recompute flagged q/k elements (W exact fp32 rows, x from XtH+XtL
// contiguous f16 splits; error ~2^-22, same as R21).
// ---------------------------------------------------------------------------
__global__ __launch_bounds__(256) void k_fix(
    const unsigned* __restrict__ flagbits,
    const float* __restrict__ wqkv,
    const f16* __restrict__ XtH, const f16* __restrict__ XtL,
    const float* __restrict__ sA, const float* __restrict__ bA,
    signed char* __restrict__ qw, signed char* __restrict__ kw)
{
  const int wv = blockIdx.x * 4 + (threadIdx.x >> 6);   // (b,n) column id
  const int lane = threadIdx.x & 63;                    // k = lane*8
  const int b = wv >> 10, n = wv & 1023;

  const unsigned* bm = flagbits + ((size_t)wv << 5);
  const unsigned myw = (lane < 32) ? bm[lane] : 0u;
  if (__ballot(myw != 0) == 0ULL) return;

  const int kb = lane * 8;
  const f16x8 bhv = *(const f16x8*)&XtH[
      frag_off(b * 8 + (n >> 7), kb >> 5, n & 127, kb & 31)];
  const f16x8 blv = *(const f16x8*)&XtL[((size_t)b * NP + n) * C + kb];
  float xv[8];
#pragma unroll
  for (int q = 0; q < 8; ++q) xv[q] = (float)bhv[q] + (float)blv[q];

  for (int w = 0; w < 32; ++w) {
    unsigned bits = __shfl(myw, w);
    while (bits) {
      const int o = w * 32 + __builtin_ctz(bits);
      bits &= bits - 1;
      const float4 w0 = *(const float4*)&wqkv[(size_t)o * C + kb];
      const float4 w1 = *(const float4*)&wqkv[(size_t)o * C + kb + 4];
      float s = 0.f;
      s = fmaf(w0.x, xv[0], s); s = fmaf(w0.y, xv[1], s);
      s = fmaf(w0.z, xv[2], s); s = fmaf(w0.w, xv[3], s);
      s = fmaf(w1.x, xv[4], s); s = fmaf(w1.y, xv[5], s);
      s = fmaf(w1.z, xv[6], s); s = fmaf(w1.w, xv[7], s);
      s += __shfl_xor(s, 1);  s += __shfl_xor(s, 2);  s += __shfl_xor(s, 4);
      s += __shfl_xor(s, 8);  s += __shfl_xor(s, 16); s += __shfl_xor(s, 32);
      if (lane == 0) {
        const float y = fmaf(s, sA[o], bA[o]);
        const signed char sg = (signed char)((y > 0.f) - (y < 0.f));
        if (o < 512) qw[((size_t)b * C + o) * NP + n] = sg;
        else         kw[((size_t)b * C + (o - 512)) * NP + n] = sg;
      }
    }
  }
}

// ---------------------------------------------------------------------------
// Fused attention: per (b,h, n-half): S = q.k^T via i8 MFMA (exact),
// wave-parallel softmax, P -> f16 hi/lo in LDS, PV via f16 MFMA.
// Output written in frag layout (proj's B operand).
// ---------------------------------------------------------------------------
__global__ __launch_bounds__(256) void k_attn_fused(
    const signed char* __restrict__ qw, const signed char* __restrict__ kw,
    const f16* __restrict__ vt, f16* __restrict__ aot)
{
  const int half = blockIdx.x;
  const int bh = blockIdx.y;
  const int b = bh >> 3, h = bh & 7;
  const int t = threadIdx.x, lane = t & 63, wid = t >> 6;
  const int dw = wid * 16;
  const int lr = lane & 15, lg = lane >> 4;

  __shared__ f16 ph[64][72];
  __shared__ f16 pl[64][72];
  __shared__ f16 sb[64][72];

  const signed char* qp = qw + ((size_t)b * C + h * HD + dw + lr) * NP;
  const signed char* kp = kw + ((size_t)b * C + h * HD + lr) * NP;

  i32x4 accS[4];
#pragma unroll
  for (int j = 0; j < 4; ++j) accS[j] = (i32x4){0, 0, 0, 0};

#pragma unroll 4
  for (int ks = 0; ks < 16; ++ks) {
    const i32x4 af = *(const i32x4*)(qp + ks * 64 + lg * 16);
#pragma unroll
    for (int j = 0; j < 4; ++j) {
      const i32x4 bf = *(const i32x4*)(kp + (size_t)(j * 16) * NP + ks * 64 + lg * 16);
      accS[j] = __builtin_amdgcn_mfma_i32_16x16x64_i8(af, bf, accS[j], 0, 0, 0);
    }
  }

#pragma unroll
  for (int r = 0; r < 4; ++r) {
    float mx = (float)accS[0][r];
#pragma unroll
    for (int j = 1; j < 4; ++j) mx = fmaxf(mx, (float)accS[j][r]);
    mx = fmaxf(mx, __shfl_xor(mx, 1));
    mx = fmaxf(mx, __shfl_xor(mx, 2));
    mx = fmaxf(mx, __shfl_xor(mx, 4));
    mx = fmaxf(mx, __shfl_xor(mx, 8));
    float pvv[4];
    float sm = 0.f;
#pragma unroll
    for (int j = 0; j < 4; ++j) {
      pvv[j] = expf(((float)accS[j][r] - mx) * 0.125f);
      sm += pvv[j];
    }
    sm += __shfl_xor(sm, 1);
    sm += __shfl_xor(sm, 2);
    sm += __shfl_xor(sm, 4);
    sm += __shfl_xor(sm, 8);
    const float inv = 1.f / sm;
    const int drow = dw + lg * 4 + r;
#pragma unroll
    for (int j = 0; j < 4; ++j) {
      const float p = pvv[j] * inv;
      const f16 hi = (f16)p;
      ph[drow][j * 16 + lr] = hi;
      pl[drow][j * 16 + lr] = (f16)(p - (float)hi);
    }
  }
  __syncthreads();

  const f16x8 pa0h = *(const f16x8*)&ph[dw + lr][lg * 8];
  const f16x8 pa0l = *(const f16x8*)&pl[dw + lr][lg * 8];
  const f16x8 pa1h = *(const f16x8*)&ph[dw + lr][32 + lg * 8];
  const f16x8 pa1l = *(const f16x8*)&pl[dw + lr][32 + lg * 8];

  const f16* vbase = vt + (size_t)b * NP * C + h * HD;
  const int nbase = half * 512;

  for (int nc = 0; nc < 8; ++nc) {
    const int nn0 = nbase + nc * 64;
    __syncthreads();
#pragma unroll
    for (int nt = 0; nt < 4; ++nt) {
      const f16* vp = vbase + (size_t)(nn0 + nt * 16 + lr) * C + lg * 8;
      const f16x8 bv0 = *(const f16x8*)(vp);
      const f16x8 bv1 = *(const f16x8*)(vp + 32);
      f32x4 acc = (f32x4){0.f, 0.f, 0.f, 0.f};
      acc = __builtin_amdgcn_mfma_f32_16x16x32_f16(pa0h, bv0, acc, 0, 0, 0);
      acc = __builtin_amdgcn_mfma_f32_16x16x32_f16(pa0l, bv0, acc, 0, 0, 0);
      acc = __builtin_amdgcn_mfma_f32_16x16x32_f16(pa1h, bv1, acc, 0, 0, 0);
      acc = __builtin_amdgcn_mfma_f32_16x16x32_f16(pa1l, bv1, acc, 0, 0, 0);
      f16x4 pk;
#pragma unroll
      for (int r = 0; r < 4; ++r) pk[r] = (f16)acc[r];
      *(f16x4*)&sb[nt * 16 + lr][dw + lg * 4] = pk;
    }
    __syncthreads();
    const int nl = t >> 2, cc = (t & 3) * 16;
    const f16x8 o0 = *(const f16x8*)&sb[nl][cc];
    const f16x8 o1 = *(const f16x8*)&sb[nl][cc + 8];
    const int n_abs = nn0 + nl;
    const int c1 = h * HD + cc, c2 = h * HD + cc + 8;
    *(f16x8*)&aot[frag_off(b * 8 + (n_abs >> 7), c1 >> 5, n_abs & 127, c1 & 31)] = o0;
    *(f16x8*)&aot[frag_off(b * 8 + (n_abs >> 7), c2 >> 5, n_abs & 127, c2 & 31)] = o1;
  }
}

// ---------------------------------------------------------------------------
// proj GEMM, HYBRID paths + single-barrier 3-buffer rotation + residual.
// ---------------------------------------------------------------------------
__global__ __launch_bounds__(256, 3) void k_proj_mfma(
    const f16* __restrict__ Wph, const f16* __restrict__ aot,
    const float* __restrict__ X, float* __restrict__ out)
{
  __shared__ __align__(16) f16 SMEM[24576];  // B buf0/1/2, 8192 f16 each

  const int t = threadIdx.x, lane = t & 63, wid = t >> 6;
  const int n0 = blockIdx.x * 128, m0 = blockIdx.y * 128, b = blockIdx.z;

  const f16* Af = Wph + (size_t)(m0 >> 7) * 65536;
  const f16* Bf = aot + ((size_t)b * 8 + (n0 >> 7)) * 65536;

  f32x4 acc[4][4];
#pragma unroll
  for (int i = 0; i < 4; ++i)
#pragma unroll
    for (int j = 0; j < 4; ++j) acc[i][j] = (f32x4){0.f, 0.f, 0.f, 0.f};

  const int wm = wid >> 1, wn = wid & 1;
  const int lr = lane & 15, ls = lane >> 4;

#define ALOAD(TI, AR) do {                                              \
    _Pragma("unroll")                                                   \
    for (int u_ = 0; u_ < 8; ++u_)                                      \
      (AR)[u_] = *(const f16x8*)&Af[(size_t)(TI) * 8192 +               \
          ((u_ >> 2) * 8 + wm * 4 + (u_ & 3)) * 512 + lane * 8];        \
  } while (0)

#define BSTAGE(TI, K) do {                                              \
    const f16* Bk_ = Bf + (size_t)(TI) * 8192;                          \
    _Pragma("unroll")                                                   \
    for (int r_ = 0; r_ < 4; ++r_)                                      \
      gld16(Bk_ + r_ * 2048 + t * 8, &SMEM[(K) * 8192 + r_ * 2048 + wid * 512]); \
  } while (0)

#define PCOMP(AR, K) do {                                               \
    _Pragma("unroll")                                                   \
    for (int ksub_ = 0; ksub_ < 2; ++ksub_) {                           \
      f16x8 bh_[4];                                                     \
      _Pragma("unroll")                                                 \
      for (int j_ = 0; j_ < 4; ++j_)                                    \
        bh_[j_] = *(const f16x8*)&SMEM[(K) * 8192 + ksub_ * 4096 +      \
            (wn * 4 + j_) * 512 + lane * 8];                            \
      _Pragma("unroll")                                                 \
      for (int i_ = 0; i_ < 4; ++i_)                                    \
        _Pragma("unroll")                                               \
        for (int j_ = 0; j_ < 4; ++j_)                                  \
          acc[i_][j_] = __builtin_amdgcn_mfma_f32_16x16x32_f16(         \
              (AR)[ksub_ * 4 + i_], bh_[j_], acc[i_][j_], 0, 0, 0);     \
    }                                                                   \
  } while (0)

  {
    f16x8 a0[8], a1[8];
    ALOAD(0, a0);
    BSTAGE(0, 0);
    BSTAGE(1, 1);
#pragma unroll
    for (int ti = 0; ti < 8; ++ti) {
      if (ti == 0)      asm volatile("s_waitcnt vmcnt(4)"  ::: "memory");
      else if (ti < 7)  asm volatile("s_waitcnt vmcnt(12)" ::: "memory");
      else              asm volatile("s_waitcnt vmcnt(0)"  ::: "memory");
      __builtin_amdgcn_sched_barrier(0);
      __builtin_amdgcn_s_barrier();
      if (ti + 1 < 8) { if ((ti + 1) & 1) ALOAD(ti + 1, a1); else ALOAD(ti + 1, a0); }
      if (ti + 2 < 8) BSTAGE(ti + 2, (ti + 2) % 3);
      if (ti & 1) PCOMP(a1, ti % 3); else PCOMP(a0, ti % 3);
    }
  }

#undef ALOAD
#undef BSTAGE
#undef PCOMP

#pragma unroll
  for (int i = 0; i < 4; ++i) {
    const int oc0 = m0 + wm * 64 + i * 16 + ls * 4;
#pragma unroll
    for (int j = 0; j < 4; ++j) {
      const int n = n0 + wn * 64 + j * 16 + lr;
#pragma unroll
      for (int r = 0; r < 4; ++r) {
        const size_t idx = ((size_t)b * C + oc0 + r) * NP + n;
        out[idx] = acc[i][j][r] + X[idx];
      }
    }
  }
}

// ---------------------------------------------------------------------------
extern "C" void kernel_launch(void* const* d_in, const int* in_sizes, int n_in,
                              void* d_out, int out_size, void* d_ws, size_t ws_size,
                              hipStream_t stream)
{
  const float* x      = (const float*)d_in[0];
  const float* w_qkv  = (const float*)d_in[1];
  const float* w_proj = (const float*)d_in[2];
  const float* g      = (const float*)d_in[3];
  const float* be     = (const float*)d_in[4];
  const float* mu     = (const float*)d_in[5];
  const float* va     = (const float*)d_in[6];
  float* out = (float*)d_out;

  char* ws = (char*)d_ws;
  f16*  Whi = (f16*)(ws + OFF_WHI);
  f16*  Wph = (f16*)(ws + OFF_WPH);
  float* sA = (float*)(ws + OFF_SB);
  float* bA = sA + M3;
  float* wn = (float*)(ws + OFF_WN);
  float* xn2 = (float*)(ws + OFF_XN);
  unsigned* flagbits = (unsigned*)(ws + OFF_FLAG);
  f16*  XtH = (f16*)(ws + OFF_XTH);
  f16*  XtL = (f16*)(ws + OFF_XTL);
  f16*  aot = (f16*)(ws + OFF_AOT);
  signed char* qw = (signed char*)(ws + OFF_Q);
  signed char* kw = (signed char*)(ws + OFF_K);
  f16*  vtw = (f16*)(ws + OFF_VT);

  // xnorm2 and flagbits are contiguous: one memset for both
  hipMemsetAsync(xn2, 0, OFF_XTH - OFF_XN, stream);

  k_convW<<<dim3(384), 256, 0, stream>>>(
      w_qkv, w_proj, g, be, mu, va, Whi, Wph, sA, bA, wn);
  k_convX<<<dim3(C / 64, NP / 64, BB), 256, 0, stream>>>(x, XtH, XtL, xn2);
  k_qkv_mfma<<<dim3(NP / 128, M3 / 128, BB), 256, 0, stream>>>(
      Whi, XtH, sA, bA, wn, xn2, qw, kw, vtw, flagbits);
  k_fix<<<dim3(BB * NP / 4), 256, 0, stream>>>(
      flagbits, w_qkv, XtH, XtL, sA, bA, qw, kw);
  k_attn_fused<<<dim3(2, BB * NH), 256, 0, stream>>>(qw, kw, vtw, aot);
  k_proj_mfma<<<dim3(NP / 128, C / 128, BB), 256, 0, stream>>>(Wph, aot, x, out);
}